// Round 5
// baseline (124.746 us; speedup 1.0000x reference)
//
#include <hip/hip_runtime.h>
#include <math.h>

#define N_NODES 131072
#define H 256
#define HH 128
#define B_GRAPHS 512

typedef __attribute__((ext_vector_type(8))) _Float16 half8;
typedef __attribute__((ext_vector_type(2))) _Float16 half2v;
typedef __attribute__((ext_vector_type(16))) float f32x16;

__device__ __forceinline__ uint packh(_Float16 h0, _Float16 h1) {
  half2v t;
  t[0] = h0; t[1] = h1;
  return __builtin_bit_cast(uint, t);
}

// ---------------- K0: pre-split W1 into 2 fp16 planes (plane1 residual x4096),
// stored transposed [p][col][k] ----------------
__global__ void k_prep_w1(const float* __restrict__ W1, ushort* __restrict__ W1h) {
  const int idx = blockIdx.x * 256 + threadIdx.x;  // 32768 = 256*128
  const int k = idx >> 7, c = idx & 127;
  const float v = W1[idx];  // W1 is [256][128] row-major
  const _Float16 h1 = (_Float16)v;
  const float r = (v - (float)h1) * 4096.f;
  const _Float16 h2 = (_Float16)r;
  W1h[0 * 32768 + c * 256 + k] = __builtin_bit_cast(ushort, h1);
  W1h[1 * 32768 + c * 256 + k] = __builtin_bit_cast(ushort, h2);
}

// ---------------- K1: segment bounds (batch is sorted) ----------------
__global__ void k_seg_bounds(const int* __restrict__ batch, int* __restrict__ seg_start,
                             int N, int B) {
  int b = blockIdx.x * blockDim.x + threadIdx.x;
  if (b > B) return;
  int lo = 0, hi = N;
  while (lo < hi) {
    int mid = (lo + hi) >> 1;
    if (batch[mid] < b) lo = mid + 1; else hi = mid;
  }
  seg_start[b] = lo;
}

// ---------------- K2: score MLP via scaled fp16 2-split MFMA ----------------
// Tile 128x128, 4 waves 2x2 (wave tile 64x64), K-step 32, 2 barriers/iter (R2 schedule).
// 3 MFMA products per (i,j) pair: acc1 += a1*b1 ; acc2 += a1*b2 + a2*b1 ; s = acc1 + acc2/4096.
__global__ __launch_bounds__(256, 2) void k_score_mfma(
    const float* __restrict__ x, const ushort* __restrict__ W1h,
    const float* __restrict__ b1, const float* __restrict__ W2,
    const float* __restrict__ b2, float* __restrict__ s_out) {
  // A planes [2][128][40] + B planes [2][128][40], fp16 (40960 B); epilogue reuses as part[]
  __shared__ ushort smem[20480];
  const int t = threadIdx.x;
  const int lane = t & 63;
  const int w = t >> 6;
  const int wr = w >> 1, wc = w & 1;
  const int nl = lane & 31, g = lane >> 5;
  const int node0 = blockIdx.x * 128;

  const int srow = t >> 1;   // 0..127
  const int shalf = t & 1;   // covers k = shalf*16 .. +16

  const f32x16 zero = (f32x16)0.0f;
  f32x16 acc1[2][2], acc2[2][2];
#pragma unroll
  for (int i = 0; i < 2; ++i)
#pragma unroll
    for (int j = 0; j < 2; ++j) { acc1[i][j] = zero; acc2[i][j] = zero; }

  // staging registers
  float4 gxA[4];
  uint4 gB[2][2];

  const float* xrow = x + (size_t)(node0 + srow) * H + shalf * 16;
  const ushort* wrow = W1h + srow * 256 + shalf * 16;  // srow doubles as B col

  // prologue: load tile 0
#pragma unroll
  for (int q = 0; q < 4; ++q) gxA[q] = *(const float4*)(xrow + q * 4);
#pragma unroll
  for (int p = 0; p < 2; ++p) {
    gB[p][0] = *(const uint4*)(wrow + p * 32768);
    gB[p][1] = *(const uint4*)(wrow + p * 32768 + 8);
  }

#pragma unroll
  for (int it = 0; it < 8; ++it) {
    // ---- stage: split x into fp16 planes, copy B planes ----
    {
      uint mainw[8], residw[8];
#pragma unroll
      for (int q = 0; q < 4; ++q) {
        const float vv[4] = {gxA[q].x, gxA[q].y, gxA[q].z, gxA[q].w};
#pragma unroll
        for (int p = 0; p < 2; ++p) {
          const float v0 = vv[2 * p], v1 = vv[2 * p + 1];
          const _Float16 h0 = (_Float16)v0, h1 = (_Float16)v1;
          const float r0 = (v0 - (float)h0) * 4096.f;
          const float r1 = (v1 - (float)h1) * 4096.f;
          mainw[2 * q + p] = packh(h0, h1);
          residw[2 * q + p] = packh((_Float16)r0, (_Float16)r1);
        }
      }
      uint4* a0 = (uint4*)&smem[0 * 5120 + srow * 40 + shalf * 16];
      uint4* a1 = (uint4*)&smem[1 * 5120 + srow * 40 + shalf * 16];
      a0[0] = make_uint4(mainw[0], mainw[1], mainw[2], mainw[3]);
      a0[1] = make_uint4(mainw[4], mainw[5], mainw[6], mainw[7]);
      a1[0] = make_uint4(residw[0], residw[1], residw[2], residw[3]);
      a1[1] = make_uint4(residw[4], residw[5], residw[6], residw[7]);
#pragma unroll
      for (int p = 0; p < 2; ++p) {
        uint4* bp = (uint4*)&smem[10240 + p * 5120 + srow * 40 + shalf * 16];
        bp[0] = gB[p][0];
        bp[1] = gB[p][1];
      }
    }
    __syncthreads();
    // ---- prefetch tile it+1 (consumed next iter -> one compute phase of latency hiding) ----
    if (it < 7) {
      const int kc = (it + 1) * 32;
#pragma unroll
      for (int q = 0; q < 4; ++q) gxA[q] = *(const float4*)(xrow + kc + q * 4);
#pragma unroll
      for (int p = 0; p < 2; ++p) {
        gB[p][0] = *(const uint4*)(wrow + p * 32768 + kc);
        gB[p][1] = *(const uint4*)(wrow + p * 32768 + kc + 8);
      }
    }
    // ---- compute: 2 substeps x 12 MFMA ----
#pragma unroll
    for (int sub = 0; sub < 2; ++sub) {
      half8 a[2][2], b[2][2];
#pragma unroll
      for (int p = 0; p < 2; ++p) {
#pragma unroll
        for (int i = 0; i < 2; ++i)
          a[p][i] = *(const half8*)&smem[p * 5120 + (wr * 64 + i * 32 + nl) * 40 +
                                         sub * 16 + g * 8];
#pragma unroll
        for (int j = 0; j < 2; ++j)
          b[p][j] = *(const half8*)&smem[10240 + p * 5120 + (wc * 64 + j * 32 + nl) * 40 +
                                         sub * 16 + g * 8];
      }
#pragma unroll
      for (int i = 0; i < 2; ++i)
#pragma unroll
        for (int j = 0; j < 2; ++j) {
          acc1[i][j] = __builtin_amdgcn_mfma_f32_32x32x16_f16(a[0][i], b[0][j], acc1[i][j], 0, 0, 0);
          acc2[i][j] = __builtin_amdgcn_mfma_f32_32x32x16_f16(a[0][i], b[1][j], acc2[i][j], 0, 0, 0);
          acc2[i][j] = __builtin_amdgcn_mfma_f32_32x32x16_f16(a[1][i], b[0][j], acc2[i][j], 0, 0, 0);
        }
    }
    __syncthreads();
  }

  // ---- epilogue: layer 2 in fp32 (proven mapping) ----
  float* part = (float*)smem;  // [128][64] = 32 KB <= 40960
  const float inv4096 = 2.44140625e-4f;
  const int col0 = wc * 64 + nl;
  const float b1v0 = b1[col0], b1v1 = b1[col0 + 32];
  const float w2v0 = W2[col0], w2v1 = W2[col0 + 32];
#pragma unroll
  for (int i = 0; i < 2; ++i) {
#pragma unroll
    for (int r = 0; r < 16; ++r) {
      const int nodeL = wr * 64 + i * 32 + (r & 3) + 8 * (r >> 2) + 4 * g;
      const float h0 = acc1[i][0][r] + acc2[i][0][r] * inv4096 + b1v0;
      const float h1 = acc1[i][1][r] + acc2[i][1][r] * inv4096 + b1v1;
      const float p = fmaxf(h0, 0.f) * w2v0 + fmaxf(h1, 0.f) * w2v1;
      part[nodeL * 64 + wc * 32 + nl] = p;
    }
  }
  __syncthreads();
  if (t < 128) {
    float sv = b2[0];
#pragma unroll 8
    for (int cc = 0; cc < 64; ++cc) {
      const int c2 = (cc + t) & 63;
      sv += part[t * 64 + c2];
    }
    s_out[node0 + t] = sv;
  }
}

// ---------------- K3: fused softmax stats + top-k select + single-pass pools ----------------
__global__ __launch_bounds__(512) void k_pool_fused(const float* __restrict__ x,
                                                    const float* __restrict__ s,
                                                    const int* __restrict__ seg_start,
                                                    float* __restrict__ pooled) {
  const int b = blockIdx.x;
  const int t = threadIdx.x;
  const int start = seg_start[b];
  const int end = seg_start[b + 1];
  const int n = end - start;

  __shared__ float s_lds[1024];
  __shared__ float red[512];
  __shared__ float thr_sh;
  __shared__ int thri_sh;
  __shared__ float r4[8][264];

  const bool fits = (n <= 1024);
  if (fits) {
    for (int i = t; i < n; i += 512) s_lds[i] = s[start + i];
  }
  __syncthreads();
  const float* sseg = fits ? s_lds : (s + start);

  float m = -INFINITY;
  for (int i = t; i < n; i += 512) m = fmaxf(m, sseg[i]);
  red[t] = m;
  __syncthreads();
  for (int off = 256; off > 0; off >>= 1) {
    if (t < off) red[t] = fmaxf(red[t], red[t + off]);
    __syncthreads();
  }
  const float smax = red[0];
  __syncthreads();
  float d = 0.f;
  for (int i = t; i < n; i += 512) d += __expf(sseg[i] - smax);
  red[t] = d;
  __syncthreads();
  for (int off = 256; off > 0; off >>= 1) {
    if (t < off) red[t] += red[t + off];
    __syncthreads();
  }
  const float denom = red[0];
  __syncthreads();
  const float inv_denom = (denom > 0.f) ? 1.f / denom : 0.f;

  int k = 0;
  if (n > 0) {
    k = (int)ceilf(0.05f * (float)n);
    if (k < 5) k = 5;
    if (k > 64) k = 64;
    if (k > n) k = n;
  }

  if (t < 64) {
    float pk = INFINITY;
    int pidx = -1;
    for (int r = 0; r < k; ++r) {
      float bk = -INFINITY;
      int bi = 0x7fffffff;
      for (int i = t; i < n; i += 64) {
        const float si = sseg[i];
        const int gi = start + i;
        const bool below = (si < pk) || (si == pk && gi > pidx);
        if (below && (si > bk || (si == bk && gi < bi))) { bk = si; bi = gi; }
      }
#pragma unroll
      for (int off = 32; off > 0; off >>= 1) {
        const float ok = __shfl_xor(bk, off);
        const int oi = __shfl_xor(bi, off);
        if (ok > bk || (ok == bk && oi < bi)) { bk = ok; bi = oi; }
      }
      pk = bk;
      pidx = bi;
    }
    if (t == 0) {
      thr_sh = (k > 0) ? pk : INFINITY;
      thri_sh = (k > 0) ? pidx : -1;
    }
  }
  __syncthreads();
  const float thr = thr_sh;
  const int thri = thri_sh;

  const int fq = t & 63;
  const int sub = t >> 6;
  float mean[4] = {0.f, 0.f, 0.f, 0.f};
  float attn[4] = {0.f, 0.f, 0.f, 0.f};
  float tk[4] = {0.f, 0.f, 0.f, 0.f};
  float mx[4] = {-INFINITY, -INFINITY, -INFINITY, -INFINITY};
  for (int i = sub; i < n; i += 8) {
    const float si = sseg[i];
    const float wi = __expf(si - smax);
    const int gi = start + i;
    const bool sel = (si > thr) || (si == thr && gi <= thri);
    const float4 xv = *reinterpret_cast<const float4*>(x + (size_t)gi * H + fq * 4);
    mean[0] += xv.x; mean[1] += xv.y; mean[2] += xv.z; mean[3] += xv.w;
    attn[0] = fmaf(xv.x, wi, attn[0]);
    attn[1] = fmaf(xv.y, wi, attn[1]);
    attn[2] = fmaf(xv.z, wi, attn[2]);
    attn[3] = fmaf(xv.w, wi, attn[3]);
    mx[0] = fmaxf(mx[0], xv.x);
    mx[1] = fmaxf(mx[1], xv.y);
    mx[2] = fmaxf(mx[2], xv.z);
    mx[3] = fmaxf(mx[3], xv.w);
    if (sel) {
      tk[0] += xv.x; tk[1] += xv.y; tk[2] += xv.z; tk[3] += xv.w;
    }
  }
  float* po = pooled + (size_t)b * 1024;
  const float invn = 1.f / (float)(n > 0 ? n : 1);
  const float invk = (k > 0) ? 1.f / (float)k : 0.f;
  *reinterpret_cast<float4*>(&r4[sub][fq * 4]) = make_float4(mean[0], mean[1], mean[2], mean[3]);
  __syncthreads();
  if (t < 256) {
    float tot = 0.f;
#pragma unroll
    for (int q = 0; q < 8; ++q) tot += r4[q][t];
    po[t] = tot * invn;
  }
  __syncthreads();
  *reinterpret_cast<float4*>(&r4[sub][fq * 4]) = make_float4(attn[0], attn[1], attn[2], attn[3]);
  __syncthreads();
  if (t < 256) {
    float tot = 0.f;
#pragma unroll
    for (int q = 0; q < 8; ++q) tot += r4[q][t];
    po[256 + t] = tot * inv_denom;
  }
  __syncthreads();
  *reinterpret_cast<float4*>(&r4[sub][fq * 4]) = make_float4(mx[0], mx[1], mx[2], mx[3]);
  __syncthreads();
  if (t < 256) {
    float tot = -INFINITY;
#pragma unroll
    for (int q = 0; q < 8; ++q) tot = fmaxf(tot, r4[q][t]);
    po[512 + t] = (n > 0) ? tot : 0.f;
  }
  __syncthreads();
  *reinterpret_cast<float4*>(&r4[sub][fq * 4]) = make_float4(tk[0], tk[1], tk[2], tk[3]);
  __syncthreads();
  if (t < 256) {
    float tot = 0.f;
#pragma unroll
    for (int q = 0; q < 8; ++q) tot += r4[q][t];
    po[768 + t] = tot * invk;
  }
}

// ---------------- K5: final GEMM [512,1024]@[1024,256], split-K=8 ----------------
__global__ __launch_bounds__(256) void k_gemm(const float* __restrict__ pooled,
                                              const float* __restrict__ Wf,
                                              float* __restrict__ gacc) {
  const int t = threadIdx.x;
  const int r0 = blockIdx.x * 8;
  const int kc0 = blockIdx.y * 128;
  __shared__ float ps[8][132];
  {
    const int r = t >> 5;
    const int c = (t & 31) << 2;
    *reinterpret_cast<float4*>(&ps[r][c]) =
        *reinterpret_cast<const float4*>(pooled + (size_t)(r0 + r) * 1024 + kc0 + c);
  }
  __syncthreads();
  float acc[8];
#pragma unroll
  for (int r = 0; r < 8; ++r) acc[r] = 0.f;
#pragma unroll 4
  for (int c = 0; c < 128; ++c) {
    const float wf = Wf[(size_t)(kc0 + c) * 256 + t];
#pragma unroll
    for (int r = 0; r < 8; ++r) acc[r] = fmaf(ps[r][c], wf, acc[r]);
  }
  float* go = gacc + ((size_t)blockIdx.y * B_GRAPHS + r0) * 256;
#pragma unroll
  for (int r = 0; r < 8; ++r) go[r * 256 + t] = acc[r];
}

// ---------------- K6: reduce split-K + bias + relu -> out ----------------
__global__ __launch_bounds__(256) void k_out(const float* __restrict__ gacc,
                                             const float* __restrict__ bf,
                                             float* __restrict__ out) {
  const int i = blockIdx.x * 256 + threadIdx.x;
  float v = bf[i & 255];
#pragma unroll
  for (int ks = 0; ks < 8; ++ks) v += gacc[(size_t)ks * (B_GRAPHS * 256) + i];
  out[i] = fmaxf(v, 0.f);
}

extern "C" void kernel_launch(void* const* d_in, const int* in_sizes, int n_in,
                              void* d_out, int out_size, void* d_ws, size_t ws_size,
                              hipStream_t stream) {
  const float* x  = (const float*)d_in[0];
  const int* batch = (const int*)d_in[1];
  const float* W1 = (const float*)d_in[2];
  const float* b1 = (const float*)d_in[3];
  const float* W2 = (const float*)d_in[4];
  const float* b2 = (const float*)d_in[5];
  const float* Wf = (const float*)d_in[6];
  const float* bf = (const float*)d_in[7];
  const int N = in_sizes[1];     // 131072
  const int B = B_GRAPHS;

  // ws floats: s[N] | seg_start[1024 ints] | pooled[B*1024] | gacc[8*B*256] | W1h[2*32768 u16]
  float* ws = (float*)d_ws;
  float* s = ws;
  int* seg_start = (int*)(ws + N);
  float* pooled = ws + N + 1024;
  float* gacc = pooled + (size_t)B * 1024;
  ushort* W1h = (ushort*)(gacc + (size_t)8 * B * 256);

  k_prep_w1<<<dim3(128), dim3(256), 0, stream>>>(W1, W1h);
  k_seg_bounds<<<dim3((B + 1 + 255) / 256), dim3(256), 0, stream>>>(batch, seg_start, N, B);
  k_score_mfma<<<dim3(N / 128), dim3(256), 0, stream>>>(x, W1h, b1, W2, b2, s);
  k_pool_fused<<<dim3(B), dim3(512), 0, stream>>>(x, s, seg_start, pooled);
  k_gemm<<<dim3(B / 8, 8), dim3(256), 0, stream>>>(pooled, Wf, gacc);
  k_out<<<dim3((B * 256) / 256), dim3(256), 0, stream>>>(gacc, bf, (float*)d_out);
}

// Round 6
// 121.537 us; speedup vs baseline: 1.0264x; 1.0264x over previous
//
#include <hip/hip_runtime.h>
#include <math.h>

#define H 256
#define HH 128
#define B_GRAPHS 512

typedef __attribute__((ext_vector_type(8))) _Float16 half8;
typedef __attribute__((ext_vector_type(16))) float f32x16;

__device__ __forceinline__ void gload16(const void* g, void* l) {
  __builtin_amdgcn_global_load_lds((const __attribute__((address_space(1))) void*)g,
                                   (__attribute__((address_space(3))) void*)l, 16, 0, 0);
}

// ---------------- K0: pre-split W1 into 2 fp16 planes (residual x4096), fragment-major ----
// plane p halves: base = ((ks*2+g)*128 + col)*8 + e   where k = ks*16 + g*8 + e
__global__ void k_prep_w1(const float* __restrict__ W1, ushort* __restrict__ W1f) {
  const int idx = blockIdx.x * 256 + threadIdx.x;  // 32768 = 256*128
  const int k = idx >> 7, c = idx & 127;
  const float v = W1[idx];  // W1 is [256][128] row-major
  const _Float16 h1 = (_Float16)v;
  const float r = (v - (float)h1) * 4096.f;
  const _Float16 h2 = (_Float16)r;
  const int base = (((k >> 4) * 2 + ((k >> 3) & 1)) * 128 + c) * 8 + (k & 7);
  W1f[base] = __builtin_bit_cast(ushort, h1);
  W1f[32768 + base] = __builtin_bit_cast(ushort, h2);
}

// ---------------- K1: segment bounds (batch is sorted) ----------------
__global__ void k_seg_bounds(const int* __restrict__ batch, int* __restrict__ seg_start,
                             int N, int B) {
  int b = blockIdx.x * blockDim.x + threadIdx.x;
  if (b > B) return;
  int lo = 0, hi = N;
  while (lo < hi) {
    int mid = (lo + hi) >> 1;
    if (batch[mid] < b) lo = mid + 1; else hi = mid;
  }
  seg_start[b] = lo;
}

// ---------------- K2: score MLP, global_load_lds triple-buffer pipeline ----------------
// Block: 64 nodes x 128 hid, 4 waves (wave = 64 nodes x 32 cols), K-step 32.
// A: raw fp32 [64][32] per buf, XOR-swizzled via pre-swizzled global source; fp16-split on read.
// B: fp16 fragment-major 16KB per buf, linear copy. Counted vmcnt, raw s_barrier.
__device__ __forceinline__ void split8(const float4 v0, const float4 v1, half8& m, half8& r) {
  const float vals[8] = {v0.x, v0.y, v0.z, v0.w, v1.x, v1.y, v1.z, v1.w};
#pragma unroll
  for (int e = 0; e < 8; ++e) {
    const _Float16 h = (_Float16)vals[e];
    m[e] = h;
    r[e] = (_Float16)((vals[e] - (float)h) * 4096.f);
  }
}

__global__ __launch_bounds__(256, 2) void k_score_mfma(
    const float* __restrict__ x, const ushort* __restrict__ W1f,
    const float* __restrict__ b1, const float* __restrict__ W2,
    const float* __restrict__ b2, float* __restrict__ s_out) {
  __shared__ float asmem[3 * 2048];    // 24 KB: A bufs [3][64][32] f32
  __shared__ ushort bsmem[3 * 8192];   // 48 KB: B bufs [3][2p][2sub][2g][128col][8] fp16
  const int t = threadIdx.x;
  const int lane = t & 63;
  const int w = t >> 6;                // wave id == column group wc (0..3)
  const int nl = lane & 31, g = lane >> 5;
  const int node0 = blockIdx.x * 64;

  f32x16 acc1[2], acc2[2];
  acc1[0] = (f32x16)0.f; acc1[1] = (f32x16)0.f;
  acc2[0] = (f32x16)0.f; acc2[1] = (f32x16)0.f;

  // A staging: wave w covers rows w*16 + q*8 + (lane>>3); source chunk pre-swizzled
  const int arow = w * 16 + (lane >> 3);
  const int achunk = (lane & 7) ^ (lane >> 3);        // == chunk ^ (row&7)
  const float* agsrc = x + (size_t)(node0 + arow) * H + achunk * 4;
  // B staging: plane p = w>>1, half (w&1); per-lane 16B of the tile's 16 KB slice
  const int bp = w >> 1;
  const ushort* bgsrc = W1f + bp * 32768 + (w & 1) * 2048 + lane * 8;

#define STAGE(buf, tt)                                                         \
  do {                                                                         \
    _Pragma("unroll") for (int q = 0; q < 2; ++q)                              \
        gload16(agsrc + (tt) * 32 + q * 8 * H,                                 \
                &asmem[(buf) * 2048 + (w * 16 + q * 8) * 32]);                 \
    _Pragma("unroll") for (int j = 0; j < 4; ++j)                              \
        gload16(bgsrc + (tt) * 4096 + j * 512,                                 \
                &bsmem[(buf) * 8192 + w * 2048 + j * 512]);                    \
  } while (0)

#define COMPUTE(buf)                                                           \
  do {                                                                         \
    _Pragma("unroll") for (int sub = 0; sub < 2; ++sub) {                      \
      half8 a0[2], a1[2];                                                      \
      _Pragma("unroll") for (int i = 0; i < 2; ++i) {                          \
        const int R = i * 32 + nl;                                             \
        const int c0 = sub * 4 + g * 2;                                        \
        const float4 v0 = *(const float4*)&asmem[(buf) * 2048 + R * 32 +       \
                                                 ((c0 ^ (R & 7)) << 2)];       \
        const float4 v1 = *(const float4*)&asmem[(buf) * 2048 + R * 32 +       \
                                                 (((c0 + 1) ^ (R & 7)) << 2)]; \
        split8(v0, v1, a0[i], a1[i]);                                          \
      }                                                                        \
      const half8 bb0 = *(const half8*)&bsmem[(buf) * 8192 + 0 * 4096 +        \
                                              sub * 2048 + (g * 128 + w * 32 + nl) * 8]; \
      const half8 bb1 = *(const half8*)&bsmem[(buf) * 8192 + 1 * 4096 +        \
                                              sub * 2048 + (g * 128 + w * 32 + nl) * 8]; \
      _Pragma("unroll") for (int i = 0; i < 2; ++i) {                          \
        acc1[i] = __builtin_amdgcn_mfma_f32_32x32x16_f16(a0[i], bb0, acc1[i], 0, 0, 0); \
        acc2[i] = __builtin_amdgcn_mfma_f32_32x32x16_f16(a0[i], bb1, acc2[i], 0, 0, 0); \
        acc2[i] = __builtin_amdgcn_mfma_f32_32x32x16_f16(a1[i], bb0, acc2[i], 0, 0, 0); \
      }                                                                        \
    }                                                                          \
  } while (0)

  // prologue: stage tiles 0 and 1
  STAGE(0, 0);
  STAGE(1, 1);
  asm volatile("s_waitcnt vmcnt(6)");   // drain tile 0, keep tile 1 in flight
  __builtin_amdgcn_s_barrier();
  __builtin_amdgcn_sched_barrier(0);

#pragma unroll
  for (int it = 0; it < 8; ++it) {
    if (it < 6) STAGE((it + 2) % 3, it + 2);   // issue-early, 6 VMEM ops
    COMPUTE(it % 3);
    if (it < 6) asm volatile("s_waitcnt vmcnt(6)");       // drain tile it+1, keep it+2
    else if (it == 6) asm volatile("s_waitcnt vmcnt(0)"); // drain tile 7
    if (it < 7) {
      __builtin_amdgcn_s_barrier();
      __builtin_amdgcn_sched_barrier(0);
    }
  }
  __syncthreads();  // full drain before LDS reuse

  // ---- epilogue: layer 2 in fp32 (proven C/D mapping) ----
  float* part = (float*)bsmem;  // [64][128]
  const float inv4096 = 2.44140625e-4f;
  const int col0 = w * 32 + nl;
  const float b1v = b1[col0];
  const float w2v = W2[col0];
#pragma unroll
  for (int i = 0; i < 2; ++i) {
#pragma unroll
    for (int r = 0; r < 16; ++r) {
      const int nodeL = i * 32 + (r & 3) + 8 * (r >> 2) + 4 * g;
      const float h = acc1[i][r] + acc2[i][r] * inv4096 + b1v;
      part[nodeL * 128 + col0] = fmaxf(h, 0.f) * w2v;
    }
  }
  __syncthreads();
  if (t < 64) {
    float sv = b2[0];
#pragma unroll 8
    for (int cc = 0; cc < 128; ++cc) {
      sv += part[t * 128 + ((cc + t) & 127)];
    }
    s_out[node0 + t] = sv;
  }
#undef STAGE
#undef COMPUTE
}

// ---------------- K3: fused softmax stats + top-k select + single-pass pools ----------------
__global__ __launch_bounds__(512) void k_pool_fused(const float* __restrict__ x,
                                                    const float* __restrict__ s,
                                                    const int* __restrict__ seg_start,
                                                    float* __restrict__ pooled) {
  const int b = blockIdx.x;
  const int t = threadIdx.x;
  const int start = seg_start[b];
  const int end = seg_start[b + 1];
  const int n = end - start;

  __shared__ float s_lds[1024];
  __shared__ float red[512];
  __shared__ float thr_sh;
  __shared__ int thri_sh;
  __shared__ float r4[8][264];

  const bool fits = (n <= 1024);
  if (fits) {
    for (int i = t; i < n; i += 512) s_lds[i] = s[start + i];
  }
  __syncthreads();
  const float* sseg = fits ? s_lds : (s + start);

  float m = -INFINITY;
  for (int i = t; i < n; i += 512) m = fmaxf(m, sseg[i]);
  red[t] = m;
  __syncthreads();
  for (int off = 256; off > 0; off >>= 1) {
    if (t < off) red[t] = fmaxf(red[t], red[t + off]);
    __syncthreads();
  }
  const float smax = red[0];
  __syncthreads();
  float d = 0.f;
  for (int i = t; i < n; i += 512) d += __expf(sseg[i] - smax);
  red[t] = d;
  __syncthreads();
  for (int off = 256; off > 0; off >>= 1) {
    if (t < off) red[t] += red[t + off];
    __syncthreads();
  }
  const float denom = red[0];
  __syncthreads();
  const float inv_denom = (denom > 0.f) ? 1.f / denom : 0.f;

  int k = 0;
  if (n > 0) {
    k = (int)ceilf(0.05f * (float)n);
    if (k < 5) k = 5;
    if (k > 64) k = 64;
    if (k > n) k = n;
  }

  if (t < 64) {
    float pk = INFINITY;
    int pidx = -1;
    for (int r = 0; r < k; ++r) {
      float bk = -INFINITY;
      int bi = 0x7fffffff;
      for (int i = t; i < n; i += 64) {
        const float si = sseg[i];
        const int gi = start + i;
        const bool below = (si < pk) || (si == pk && gi > pidx);
        if (below && (si > bk || (si == bk && gi < bi))) { bk = si; bi = gi; }
      }
#pragma unroll
      for (int off = 32; off > 0; off >>= 1) {
        const float ok = __shfl_xor(bk, off);
        const int oi = __shfl_xor(bi, off);
        if (ok > bk || (ok == bk && oi < bi)) { bk = ok; bi = oi; }
      }
      pk = bk;
      pidx = bi;
    }
    if (t == 0) {
      thr_sh = (k > 0) ? pk : INFINITY;
      thri_sh = (k > 0) ? pidx : -1;
    }
  }
  __syncthreads();
  const float thr = thr_sh;
  const int thri = thri_sh;

  const int fq = t & 63;
  const int sub = t >> 6;
  float mean[4] = {0.f, 0.f, 0.f, 0.f};
  float attn[4] = {0.f, 0.f, 0.f, 0.f};
  float tk[4] = {0.f, 0.f, 0.f, 0.f};
  float mx[4] = {-INFINITY, -INFINITY, -INFINITY, -INFINITY};
  for (int i = sub; i < n; i += 8) {
    const float si = sseg[i];
    const float wi = __expf(si - smax);
    const int gi = start + i;
    const bool sel = (si > thr) || (si == thr && gi <= thri);
    const float4 xv = *reinterpret_cast<const float4*>(x + (size_t)gi * H + fq * 4);
    mean[0] += xv.x; mean[1] += xv.y; mean[2] += xv.z; mean[3] += xv.w;
    attn[0] = fmaf(xv.x, wi, attn[0]);
    attn[1] = fmaf(xv.y, wi, attn[1]);
    attn[2] = fmaf(xv.z, wi, attn[2]);
    attn[3] = fmaf(xv.w, wi, attn[3]);
    mx[0] = fmaxf(mx[0], xv.x);
    mx[1] = fmaxf(mx[1], xv.y);
    mx[2] = fmaxf(mx[2], xv.z);
    mx[3] = fmaxf(mx[3], xv.w);
    if (sel) {
      tk[0] += xv.x; tk[1] += xv.y; tk[2] += xv.z; tk[3] += xv.w;
    }
  }
  float* po = pooled + (size_t)b * 1024;
  const float invn = 1.f / (float)(n > 0 ? n : 1);
  const float invk = (k > 0) ? 1.f / (float)k : 0.f;
  *reinterpret_cast<float4*>(&r4[sub][fq * 4]) = make_float4(mean[0], mean[1], mean[2], mean[3]);
  __syncthreads();
  if (t < 256) {
    float tot = 0.f;
#pragma unroll
    for (int q = 0; q < 8; ++q) tot += r4[q][t];
    po[t] = tot * invn;
  }
  __syncthreads();
  *reinterpret_cast<float4*>(&r4[sub][fq * 4]) = make_float4(attn[0], attn[1], attn[2], attn[3]);
  __syncthreads();
  if (t < 256) {
    float tot = 0.f;
#pragma unroll
    for (int q = 0; q < 8; ++q) tot += r4[q][t];
    po[256 + t] = tot * inv_denom;
  }
  __syncthreads();
  *reinterpret_cast<float4*>(&r4[sub][fq * 4]) = make_float4(mx[0], mx[1], mx[2], mx[3]);
  __syncthreads();
  if (t < 256) {
    float tot = -INFINITY;
#pragma unroll
    for (int q = 0; q < 8; ++q) tot = fmaxf(tot, r4[q][t]);
    po[512 + t] = (n > 0) ? tot : 0.f;
  }
  __syncthreads();
  *reinterpret_cast<float4*>(&r4[sub][fq * 4]) = make_float4(tk[0], tk[1], tk[2], tk[3]);
  __syncthreads();
  if (t < 256) {
    float tot = 0.f;
#pragma unroll
    for (int q = 0; q < 8; ++q) tot += r4[q][t];
    po[768 + t] = tot * invk;
  }
}

// ---------------- K5: final GEMM [512,1024]@[1024,256], split-K=8 ----------------
__global__ __launch_bounds__(256) void k_gemm(const float* __restrict__ pooled,
                                              const float* __restrict__ Wf,
                                              float* __restrict__ gacc) {
  const int t = threadIdx.x;
  const int r0 = blockIdx.x * 8;
  const int kc0 = blockIdx.y * 128;
  __shared__ float ps[8][132];
  {
    const int r = t >> 5;
    const int c = (t & 31) << 2;
    *reinterpret_cast<float4*>(&ps[r][c]) =
        *reinterpret_cast<const float4*>(pooled + (size_t)(r0 + r) * 1024 + kc0 + c);
  }
  __syncthreads();
  float acc[8];
#pragma unroll
  for (int r = 0; r < 8; ++r) acc[r] = 0.f;
#pragma unroll 4
  for (int c = 0; c < 128; ++c) {
    const float wf = Wf[(size_t)(kc0 + c) * 256 + t];
#pragma unroll
    for (int r = 0; r < 8; ++r) acc[r] = fmaf(ps[r][c], wf, acc[r]);
  }
  float* go = gacc + ((size_t)blockIdx.y * B_GRAPHS + r0) * 256;
#pragma unroll
  for (int r = 0; r < 8; ++r) go[r * 256 + t] = acc[r];
}

// ---------------- K6: reduce split-K + bias + relu -> out ----------------
__global__ __launch_bounds__(256) void k_out(const float* __restrict__ gacc,
                                             const float* __restrict__ bf,
                                             float* __restrict__ out) {
  const int i = blockIdx.x * 256 + threadIdx.x;
  float v = bf[i & 255];
#pragma unroll
  for (int ks = 0; ks < 8; ++ks) v += gacc[(size_t)ks * (B_GRAPHS * 256) + i];
  out[i] = fmaxf(v, 0.f);
}

extern "C" void kernel_launch(void* const* d_in, const int* in_sizes, int n_in,
                              void* d_out, int out_size, void* d_ws, size_t ws_size,
                              hipStream_t stream) {
  const float* x  = (const float*)d_in[0];
  const int* batch = (const int*)d_in[1];
  const float* W1 = (const float*)d_in[2];
  const float* b1 = (const float*)d_in[3];
  const float* W2 = (const float*)d_in[4];
  const float* b2 = (const float*)d_in[5];
  const float* Wf = (const float*)d_in[6];
  const float* bf = (const float*)d_in[7];
  const int N = in_sizes[1];     // 131072
  const int B = B_GRAPHS;

  // ws floats: s[N] | seg_start[1024 ints] | pooled[B*1024] | gacc[8*B*256] | W1f[2*32768 u16]
  float* ws = (float*)d_ws;
  float* s = ws;
  int* seg_start = (int*)(ws + N);
  float* pooled = ws + N + 1024;
  float* gacc = pooled + (size_t)B * 1024;
  ushort* W1f = (ushort*)(gacc + (size_t)8 * B * 256);

  k_prep_w1<<<dim3(128), dim3(256), 0, stream>>>(W1, W1f);
  k_seg_bounds<<<dim3((B + 1 + 255) / 256), dim3(256), 0, stream>>>(batch, seg_start, N, B);
  k_score_mfma<<<dim3(N / 64), dim3(256), 0, stream>>>(x, W1f, b1, W2, b2, s);
  k_pool_fused<<<dim3(B), dim3(512), 0, stream>>>(x, s, seg_start, pooled);
  k_gemm<<<dim3(B / 8, 8), dim3(256), 0, stream>>>(pooled, Wf, gacc);
  k_out<<<dim3((B * 256) / 256), dim3(256), 0, stream>>>(gacc, bf, (float*)d_out);
}